// Round 8
// baseline (1074.010 us; speedup 1.0000x reference)
//
#include <hip/hip_runtime.h>
#include <hip/hip_bf16.h>
#include <stdint.h>
#include <stddef.h>

// QDGAT forward, MI355X gfx950.
// Round 15: GEMM-pass fusion. Per iteration, plpc / v / mu all multiply the
// SAME A (xc) by different weights. Fused: one K=1024 N=3072 GEMM against
// precomputed wcomb=[Wpc; Wv[:,D:2D]; Wmu[:,:D]] (grid 32x48=1536 blocks =
// 6/CU, best-TLP regime measured) with a segmented epilogue (seg=gn>>10,
// wave-uniform): seg0->plpc*pl (bf16), seg1->vxc=+b_v+vent (f32),
// seg2->muxc (f32). v and mu become K=1024 remainder GEMMs with addC=partial.
// Same total K-steps (80/iter) but 2 fewer full prologues and 3x parallelism
// on 48 of them. Also: 7 f2b launches -> 1 segmented kernel; 2 transw -> 1.
// GEMM core itself unchanged from R10 (best measured: 128x64, 3-buf counted).
// Inputs/outputs fp32; GEMM operands bf16 (absmax 0.031, budget 0.11).

typedef __hip_bfloat16 bf16;
typedef __attribute__((ext_vector_type(8))) short short8;
typedef __attribute__((ext_vector_type(4))) float floatx4;

#define NB 4
#define NN 1024
#define DD 1024
#define NT_ITER 4
#define MM (NB * NN) // 4096

static __device__ __forceinline__ float b2f(bf16 x) { return __bfloat162float(x); }
static __device__ __forceinline__ bf16 f2b(float x) { return __float2bfloat16(x); }
static __device__ __forceinline__ unsigned short f2bu(float x) {
    bf16 h = __float2bfloat16(x);
    unsigned short u;
    __builtin_memcpy(&u, &h, 2);
    return u;
}
static __device__ __forceinline__ float bu2f(unsigned short u) {
    unsigned int t = (unsigned int)u << 16;
    float f;
    __builtin_memcpy(&f, &t, 4);
    return f;
}

// global -> LDS direct DMA, 16 B per lane. LDS dest = wave-uniform base + lane*16.
static __device__ __forceinline__ void gl_lds16(const void* g, void* l) {
    __builtin_amdgcn_global_load_lds(
        (const __attribute__((address_space(1))) unsigned int*)g,
        (__attribute__((address_space(3))) unsigned int*)l, 16, 0, 0);
}

template <int N>
static __device__ __forceinline__ void s_wait_vmcnt() {
    if constexpr (N == 0)      asm volatile("s_waitcnt vmcnt(0)" ::: "memory");
    else if constexpr (N == 4) asm volatile("s_waitcnt vmcnt(4)" ::: "memory");
    else if constexpr (N == 6) asm volatile("s_waitcnt vmcnt(6)" ::: "memory");
    else if constexpr (N == 8) asm volatile("s_waitcnt vmcnt(8)" ::: "memory");
}

// ---------------------------------------------------------------------------
// All fp32 -> bf16 conversions in one launch (segment table by block range).
// float4-group cumulative offsets:
//   initm 256 | ents 1048576 | wpl 262144 | wpc 262144 | wv 786432
//   | wmu 524288 | wcb 524288  => total 3408128 groups (13313 blocks exact)
// ---------------------------------------------------------------------------
__global__ void k_f2b_all(const float* __restrict__ initm, const float* __restrict__ ents,
                          const float* __restrict__ wpl, const float* __restrict__ wpc,
                          const float* __restrict__ wv, const float* __restrict__ wmu,
                          const float* __restrict__ wcb,
                          bf16* __restrict__ initm_bf, bf16* __restrict__ ents_bf,
                          bf16* __restrict__ wpl_bf, bf16* __restrict__ wpc_bf,
                          bf16* __restrict__ wv_bf, bf16* __restrict__ wmu_bf,
                          bf16* __restrict__ wcb_bf) {
    long i = (long)blockIdx.x * 256 + threadIdx.x;
    const float* src;
    bf16* dst;
    long off;
    if (i < 1048832) {
        if (i < 256) { src = initm; dst = initm_bf; off = i; }
        else { src = ents; dst = ents_bf; off = i - 256; }
    } else if (i < 1573120) {
        if (i < 1310976) { src = wpl; dst = wpl_bf; off = i - 1048832; }
        else { src = wpc; dst = wpc_bf; off = i - 1310976; }
    } else if (i < 2359552) { src = wv; dst = wv_bf; off = i - 1573120; }
    else if (i < 2883840) { src = wmu; dst = wmu_bf; off = i - 2359552; }
    else { src = wcb; dst = wcb_bf; off = i - 2883840; }
    float4 v = ((const float4*)src)[off];
    ushort4 o;
    o.x = f2bu(v.x); o.y = f2bu(v.y); o.z = f2bu(v.z); o.w = f2bu(v.w);
    ((ushort4*)dst)[off] = o;
}

// ---------------------------------------------------------------------------
// fp32 (1024 x 3072) -> bf16 transposed (3072 x 1024); z selects w_q / w_k.
// ---------------------------------------------------------------------------
__global__ void k_transw2(const float* __restrict__ srcq, const float* __restrict__ srck,
                          bf16* __restrict__ dstq, bf16* __restrict__ dstk) {
    __shared__ float tile[32][33];
    const float* src = blockIdx.z ? srck : srcq;
    bf16* dst = blockIdx.z ? dstk : dstq;
    int c0 = blockIdx.x * 32;
    int r0 = blockIdx.y * 32;
    int tx = threadIdx.x, ty = threadIdx.y; // (32,8)
    for (int i = 0; i < 32; i += 8)
        tile[ty + i][tx] = src[(size_t)(r0 + ty + i) * 3072 + c0 + tx];
    __syncthreads();
    for (int i = 0; i < 32; i += 8)
        dst[(size_t)(c0 + ty + i) * 1024 + r0 + tx] = f2b(tile[tx][ty + i]);
}

// ---------------------------------------------------------------------------
// wcomb (3072 x 1024 bf16) = [Wpc ; Wv[:,D:2D] ; Wmu[:,:D]] and
// bcomb (3072 f32) = [b_pc ; b_v ; b_mu]. Runs after conversions.
// ---------------------------------------------------------------------------
__global__ void k_buildcomb(const bf16* __restrict__ wpc_bf, const bf16* __restrict__ wv_bf,
                            const bf16* __restrict__ wmu_bf,
                            const float* __restrict__ b_pc, const float* __restrict__ b_v,
                            const float* __restrict__ b_mu,
                            bf16* __restrict__ wcomb, float* __restrict__ bcomb) {
    int i = blockIdx.x * 256 + threadIdx.x; // ushort4 groups: 3072*1024/4
    if (i < 786432) {
        int r = i >> 8;
        int c4 = (i & 255) * 4;
        ushort4 v;
        if (r < 1024)      v = *(const ushort4*)(wpc_bf + (size_t)r * 1024 + c4);
        else if (r < 2048) v = *(const ushort4*)(wv_bf + (size_t)(r - 1024) * 3072 + 1024 + c4);
        else               v = *(const ushort4*)(wmu_bf + (size_t)(r - 2048) * 2048 + c4);
        ((ushort4*)wcomb)[i] = v;
    }
    if (i < 3072)
        bcomb[i] = (i < 1024) ? b_pc[i] : (i < 2048 ? b_v[i - 1024] : b_mu[i - 2048]);
}

// ---------------------------------------------------------------------------
// adj (int32, loop-invariant) -> uint8 code table, 4 elements/thread.
// code: 255 = masked (adj==0), 254 = zero-logit (type bit off), else adj-1.
// ---------------------------------------------------------------------------
__global__ void k_adjcode(const int* __restrict__ adj, const int* __restrict__ typesPtr,
                          unsigned char* __restrict__ code, int n4) {
    int i = blockIdx.x * 256 + threadIdx.x;
    if (i >= n4) return;
    int types = typesPtr[0];
    int4 a4 = ((const int4*)adj)[i];
    uchar4 c;
    int a;
    a = a4.x; c.x = (a == 0) ? 255 : (((types >> a) & 1) ? (unsigned char)(a - 1) : 254);
    a = a4.y; c.y = (a == 0) ? 255 : (((types >> a) & 1) ? (unsigned char)(a - 1) : 254);
    a = a4.z; c.z = (a == 0) ? 255 : (((types >> a) & 1) ? (unsigned char)(a - 1) : 254);
    a = a4.w; c.w = (a == 0) ? 255 : (((types >> a) & 1) ? (unsigned char)(a - 1) : 254);
    ((uchar4*)code)[i] = c;
}

// ---------------------------------------------------------------------------
// Build A matrices for the wqtw / wkeff GEMMs (64 x 1024 bf16 each).
// ---------------------------------------------------------------------------
__global__ void k_build_sc(const float* __restrict__ pk, const float* __restrict__ wes,
                           bf16* __restrict__ Aq, bf16* __restrict__ Ak) {
    int i = blockIdx.x * 256 + threadIdx.x; // 0..131071
    int half = i >> 16;
    int j = i & 65535;
    int row = j >> 10, d = j & 1023;
    if (half == 0) {
        Aq[j] = (row < 4) ? f2b(wes[(size_t)row * 2048 + d]) : f2b(0.f);
    } else {
        int t = row >> 4, b = (row >> 2) & 3, e = row & 3;
        Ak[j] = f2b(pk[((size_t)t * NB + b) * DD + d] * wes[(size_t)e * 2048 + 1024 + d]);
    }
}

// ---------------------------------------------------------------------------
// Wave-per-output GEMVs (coalesced weight-row reads, shuffle reduce).
// ---------------------------------------------------------------------------
__global__ __launch_bounds__(256) void k_qbase(const float* __restrict__ qenc, const float* __restrict__ w,
                                               const float* __restrict__ b, float* __restrict__ out) {
    int o = blockIdx.x * 4 + (threadIdx.x >> 6);
    int lane = threadIdx.x & 63;
    int n = o >> 2, r = o & 3;
    const float* xr = qenc + (size_t)r * DD;
    const float* wr = w + (size_t)n * DD;
    float s = 0.f;
    for (int d = lane; d < DD; d += 64) s += xr[d] * wr[d];
    for (int off = 32; off; off >>= 1) s += __shfl_down(s, off);
    if (lane == 0) {
        s += b[n];
        out[(size_t)r * DD + n] = s > 0.f ? s : (expf(s) - 1.0f); // ELU
    }
}

__global__ __launch_bounds__(256) void k_cmd(const float* __restrict__ qb, const float* __restrict__ w_qt,
                                             const float* __restrict__ b_qt, float* __restrict__ cmd) {
    int o = blockIdx.x * 4 + (threadIdx.x >> 6);
    int lane = threadIdx.x & 63;
    int r = o & 3, n = (o >> 2) & 1023, t = o >> 12;
    const float* xr = qb + (size_t)r * DD;
    const float* wr = w_qt + ((size_t)t * DD + n) * DD;
    float s = 0.f;
    for (int d = lane; d < DD; d += 64) s += xr[d] * wr[d];
    for (int off = 32; off; off >>= 1) s += __shfl_down(s, off);
    if (lane == 0) cmd[((size_t)t * NB + r) * DD + n] = s + b_qt[t * DD + n];
}

__global__ __launch_bounds__(256) void k_pkpv(const float* __restrict__ cmd,
                                              const float* __restrict__ w_pk, const float* __restrict__ b_pk,
                                              const float* __restrict__ w_pv, const float* __restrict__ b_pv,
                                              float* __restrict__ pk, float* __restrict__ pv) {
    int o = blockIdx.x * 4 + (threadIdx.x >> 6);
    int lane = threadIdx.x & 63;
    int n = o >> 5, half = (o >> 4) & 1, pair = o & 15;
    const float* xr = cmd + (size_t)pair * DD;
    const float* wr = (half ? w_pv : w_pk) + (size_t)n * DD;
    float s = 0.f;
    for (int d = lane; d < DD; d += 64) s += xr[d] * wr[d];
    for (int off = 32; off; off >>= 1) s += __shfl_down(s, off);
    if (lane == 0)
        (half ? pv : pk)[(size_t)pair * DD + n] = s + (half ? b_pv : b_pk)[n];
}

// One wave per output (68 outputs): cq[0..3], ck[0..63].
__global__ void k_consts(const float* __restrict__ b_q, const float* __restrict__ b_k,
                         const float* __restrict__ pk, const float* __restrict__ wes,
                         float* __restrict__ cq, float* __restrict__ ck) {
    int o = blockIdx.x;
    int lane = threadIdx.x;
    float s = 0.f;
    if (o < 4) {
        for (int d = lane; d < 1024; d += 64) s += b_q[d] * wes[(size_t)o * 2048 + d];
    } else {
        int oo = o - 4;
        int t = oo >> 4, b = (oo >> 2) & 3, e = oo & 3;
        for (int d = lane; d < 1024; d += 64)
            s += b_k[d] * pk[((size_t)t * NB + b) * DD + d] * wes[(size_t)e * 2048 + 1024 + d];
    }
    for (int off = 32; off; off >>= 1) s += __shfl_down(s, off);
    if (lane == 0) {
        if (o < 4) cq[o] = s;
        else ck[o - 4] = s;
    }
}

// ---------------------------------------------------------------------------
// qa[m,e], kb[m,e] via collapsed projections: block per row m.
// Vectorized: thread t owns d = 4t..4t+3 (ushort4 row load + float4 weights).
// ---------------------------------------------------------------------------
__global__ __launch_bounds__(256) void k_qakb2(const bf16* __restrict__ ents, const bf16* __restrict__ xc,
                                               const bf16* __restrict__ plpc,
                                               const float* __restrict__ wqtw, const float* __restrict__ wkeff_t,
                                               const float* __restrict__ cq, const float* __restrict__ ck_t,
                                               float* __restrict__ qa, float* __restrict__ kb) {
    __shared__ float red[4][8];
    int m = blockIdx.x;
    int b = m >> 10;
    int t = threadIdx.x;
    float aq[4] = {0.f, 0.f, 0.f, 0.f}, ak[4] = {0.f, 0.f, 0.f, 0.f};
    const bf16* rows[3] = {ents + (size_t)m * DD, xc + (size_t)m * DD, plpc + (size_t)m * DD};
#pragma unroll
    for (int c = 0; c < 3; ++c) {
        ushort4 rv = *(const ushort4*)(rows[c] + 4 * t);
        float xv0 = bu2f(rv.x), xv1 = bu2f(rv.y), xv2 = bu2f(rv.z), xv3 = bu2f(rv.w);
        const float* wq = wqtw + c * 1024 + 4 * t;
        const float* wk = wkeff_t + (size_t)b * 4 * 3072 + c * 1024 + 4 * t;
#pragma unroll
        for (int e = 0; e < 4; ++e) {
            float4 q4 = *(const float4*)(wq + (size_t)e * 3072);
            float4 k4 = *(const float4*)(wk + (size_t)e * 3072);
            aq[e] += xv0 * q4.x + xv1 * q4.y + xv2 * q4.z + xv3 * q4.w;
            ak[e] += xv0 * k4.x + xv1 * k4.y + xv2 * k4.z + xv3 * k4.w;
        }
    }
#pragma unroll
    for (int e = 0; e < 4; ++e) {
        float v = aq[e];
        for (int o = 32; o; o >>= 1) v += __shfl_down(v, o);
        if ((t & 63) == 0) red[t >> 6][e] = v;
        v = ak[e];
        for (int o = 32; o; o >>= 1) v += __shfl_down(v, o);
        if ((t & 63) == 0) red[t >> 6][e + 4] = v;
    }
    __syncthreads();
    if (t < 8) {
        float s = red[0][t] + red[1][t] + red[2][t] + red[3][t];
        if (t < 4) qa[(size_t)m * 4 + t] = s + cq[t];
        else kb[(size_t)m * 4 + (t - 4)] = s + ck_t[b * 4 + (t - 4)];
    }
}

// ---------------------------------------------------------------------------
// Init: x_ctx = broadcast(initm); xc = initm * mask (per row).
// ---------------------------------------------------------------------------
__global__ void k_init(const bf16* __restrict__ initm_bf, const float* __restrict__ mask,
                       bf16* __restrict__ x_ctx, bf16* __restrict__ xc) {
    int i = blockIdx.x * 256 + threadIdx.x; // uint4 groups, MM*DD/8
    uint4 v = ((const uint4*)initm_bf)[i & 127];
    ((uint4*)x_ctx)[i] = v;
    float mk = mask[i >> 7];
    unsigned short* u = (unsigned short*)&v;
#pragma unroll
    for (int j = 0; j < 8; ++j) u[j] = f2bu(bu2f(u[j]) * mk);
    ((uint4*)xc)[i] = v;
}

// ---------------------------------------------------------------------------
// BMxBN-tile GEMM: C[m,n] = sum_c A_c[m,k]*W[n,c*1024+k] (+bias)(+addC)(epilogue)
// Template WM, WN = wave-tile. Big GEMMs: <64,32> (BM=128, BN=64, R10 config,
// best measured). Precompute: <32,32>. BK=64. 4 waves as 2x2.
// Counted-vmcnt deep pipeline: 3 LDS buffers, tiles staged 2 ahead, wait
// vmcnt(SPW) per K-step (not 0), single raw s_barrier per K-step.
// Hazard proof: stage at iter kt targets buf[(kt+2)%3] = buf[(kt-1)%3]; every
// wave executed s_waitcnt lgkmcnt(0) at the end of iter kt-1 before arriving
// at iter kt's barrier, so after the barrier no wave can still be reading it.
// Tile kt's loads are proven landed by vmcnt(SPW).
// XOR bank swizzle both-sides (rule 21): linear LDS dest, pre-swizzled GLOBAL
// source column (scol ^= srow<<3, 16B granules), same XOR on ds_read side.
// A_c lda=1024; W row-major ldw; C row-major ldc. addC fp32, same index as C.
// mulmode: 0 none, 1 bf16 mul[m*1024+n], 2 f32 mul[(m>>10)*1024+n],
//          3 dual-store: C=val (bf16), C2=val*((f32*)mul)[gm] (bf16),
//          4 segmented (fused xc-GEMM, N=3072): seg=gn>>10, gl=gn&1023,
//            seg0: C[gm*1024+gl]=f2b(val*mul_bf16[gm*1024+gl])   (plpc)
//            seg1: X1[gm*1024+gl]=val+addC[gm*1024+gl]           (vxc)
//            seg2: X2[gm*1024+gl]=val                            (muxc)
// ---------------------------------------------------------------------------
template <int WM, int WN>
__device__ __forceinline__ void gemm_core(
    const bf16* __restrict__ A0, const bf16* __restrict__ A1, const bf16* __restrict__ A2,
    const bf16* __restrict__ W, const float* __restrict__ bias, void* __restrict__ C,
    const void* __restrict__ mul, const float* __restrict__ addC, bf16* __restrict__ C2,
    float* __restrict__ X1, float* __restrict__ X2,
    int mulmode, int storef32, int nchunks, int ldw, int ldc,
    int bm, int bn) {
    constexpr int BM = WM * 2;
    constexpr int BN = WN * 2;
    constexpr int MI = WM / 16;
    constexpr int NI = WN / 16;
    constexpr int SEGS = (BM + BN) / 8;
    constexpr int SPW = SEGS / 4;
    __shared__ bf16 sAB[3][(BM + BN) * 64];

    const int t = threadIdx.x;
    const int lane = t & 63;
    const int w = t >> 6;
    const int wm = (w & 1) * WM, wn = (w >> 1) * WN;
    const int srow = lane >> 3;
    const int scol = ((lane & 7) * 8) ^ (srow << 3);

    floatx4 acc[MI][NI];
#pragma unroll
    for (int i = 0; i < MI; ++i)
#pragma unroll
        for (int j = 0; j < NI; ++j) acc[i][j] = (floatx4){0.f, 0.f, 0.f, 0.f};

    const int lrow = lane & 15;
    const int kq = (lane >> 4) * 8;
    const int kx = (lane & 7) << 3;
    const int ktiles = nchunks * 16;

    auto stage = [&](int buf, int kt) {
        const int cidx = kt >> 4;
        const bf16* Ac = (cidx == 0) ? A0 : (cidx == 1 ? A1 : A2);
        const int klocal = (kt & 15) * 64;
        const int kglob = kt * 64;
#pragma unroll
        for (int s = 0; s < SPW; ++s) {
            int c = w * SPW + s;
            if (c < BM / 8) {
                const bf16* src = Ac + ((size_t)(bm * BM + c * 8 + srow)) * 1024 + klocal + scol;
                gl_lds16(src, &sAB[buf][c * 512]);
            } else {
                const bf16* src = W + ((size_t)(bn * BN + (c - BM / 8) * 8 + srow)) * (size_t)ldw + kglob + scol;
                gl_lds16(src, &sAB[buf][c * 512]);
            }
        }
    };

    stage(0, 0);
    if (ktiles > 1) stage(1, 1);
    int cur = 0, sb = 2;
    for (int kt = 0; kt < ktiles; ++kt) {
        if (kt + 1 < ktiles) s_wait_vmcnt<SPW>();
        else s_wait_vmcnt<0>();
        __builtin_amdgcn_s_barrier();
        __builtin_amdgcn_sched_barrier(0);
        short8 af[2][MI], bfr[2][NI];
#pragma unroll
        for (int ks = 0; ks < 2; ++ks) {
            const int ko = (ks * 32 + kq) ^ kx;
#pragma unroll
            for (int mi = 0; mi < MI; ++mi)
                af[ks][mi] = *(const short8*)&sAB[cur][(wm + mi * 16 + lrow) * 64 + ko];
#pragma unroll
            for (int ni = 0; ni < NI; ++ni)
                bfr[ks][ni] = *(const short8*)&sAB[cur][BM * 64 + (wn + ni * 16 + lrow) * 64 + ko];
        }
        if (kt + 2 < ktiles) stage(sb, kt + 2);
        __builtin_amdgcn_s_setprio(1);
#pragma unroll
        for (int ks = 0; ks < 2; ++ks)
#pragma unroll
            for (int mi = 0; mi < MI; ++mi)
#pragma unroll
                for (int ni = 0; ni < NI; ++ni)
                    acc[mi][ni] = __builtin_amdgcn_mfma_f32_16x16x32_bf16(af[ks][mi], bfr[ks][ni], acc[mi][ni], 0, 0, 0);
        __builtin_amdgcn_s_setprio(0);
        asm volatile("s_waitcnt lgkmcnt(0)" ::: "memory");
        __builtin_amdgcn_sched_barrier(0);
        cur = (cur == 2) ? 0 : cur + 1;
        sb = (sb == 2) ? 0 : sb + 1;
    }

    const int qrow = (lane >> 4) * 4;
#pragma unroll
    for (int mi = 0; mi < MI; ++mi) {
#pragma unroll
        for (int ni = 0; ni < NI; ++ni) {
            int gn = bn * BN + wn + ni * 16 + lrow;
            float bv = bias ? bias[gn] : 0.f;
#pragma unroll
            for (int r = 0; r < 4; ++r) {
                int gm = bm * BM + wm + mi * 16 + qrow + r;
                float val = acc[mi][ni][r] + bv;
                if (mulmode == 4) {
                    int seg = gn >> 10, gl = gn & 1023;
                    size_t li = (size_t)gm * 1024 + gl;
                    if (seg == 0)
                        ((bf16*)C)[li] = f2b(val * b2f(((const bf16*)mul)[li]));
                    else if (seg == 1)
                        X1[li] = val + addC[li];
                    else
                        X2[li] = val;
                } else {
                    size_t ci = (size_t)gm * (size_t)ldc + gn;
                    if (addC) val += addC[ci];
                    if (mulmode == 1)
                        val *= b2f(((const bf16*)mul)[(size_t)gm * 1024 + gn]);
                    else if (mulmode == 2)
                        val *= ((const float*)mul)[(size_t)(gm >> 10) * 1024 + gn];
                    if (storef32) {
                        ((float*)C)[ci] = val;
                    } else {
                        ((bf16*)C)[ci] = f2b(val);
                        if (mulmode == 3)
                            C2[ci] = f2b(val * ((const float*)mul)[gm]);
                    }
                }
            }
        }
    }
}

template <int WM, int WN>
__global__ __launch_bounds__(256) void k_gemm_t(
    const bf16* __restrict__ A0, const bf16* __restrict__ A1, const bf16* __restrict__ A2,
    const bf16* __restrict__ W, const float* __restrict__ bias, void* __restrict__ C,
    const void* __restrict__ mul, const float* __restrict__ addC, bf16* __restrict__ C2,
    float* __restrict__ X1, float* __restrict__ X2,
    int mulmode, int storef32, int nchunks, int ldw, int ldc,
    long long sA, long long sW, long long sC) {
    int bz = blockIdx.z;
    const bf16* A0b = A0 + (size_t)bz * sA;
    const bf16* Wb = W + (size_t)bz * sW;
    void* Cb = storef32 ? (void*)((float*)C + (size_t)bz * sC)
                        : (void*)((bf16*)C + (size_t)bz * sC);
    gemm_core<WM, WN>(A0b, A1, A2, Wb, bias, Cb, mul, addC, C2, X1, X2,
                      mulmode, storef32, nchunks, ldw, ldc,
                      blockIdx.x, blockIdx.y);
}

// ---------------------------------------------------------------------------
// v (B,N,D) -> vT (B,D,N)
// ---------------------------------------------------------------------------
__global__ void k_transpose(const bf16* __restrict__ v, bf16* __restrict__ vT) {
    __shared__ bf16 tile[32][33];
    int b = blockIdx.z;
    int n0 = blockIdx.x * 32, d0 = blockIdx.y * 32;
    int tx = threadIdx.x, ty = threadIdx.y; // (32,8)
    for (int i = 0; i < 32; i += 8)
        tile[ty + i][tx] = v[((size_t)b * NN + n0 + ty + i) * DD + d0 + tx];
    __syncthreads();
    for (int i = 0; i < 32; i += 8)
        vT[((size_t)b * DD + d0 + ty + i) * NN + n0 + tx] = tile[tx][ty + i];
}

// ---------------------------------------------------------------------------
// Edge scores + masked softmax from the uint8 code table: one block per row.
// Thread t owns j = 4t..4t+3; logits live in registers; two block reductions.
// ---------------------------------------------------------------------------
__global__ __launch_bounds__(256) void k_attn(const unsigned char* __restrict__ code,
                                              const float* __restrict__ qa,
                                              const float* __restrict__ kb,
                                              bf16* __restrict__ prob) {
    __shared__ float red[4];
    __shared__ float red2[4];
    int m = blockIdx.x;
    int b = m >> 10;
    int t = threadIdx.x;
    float qa0 = qa[(size_t)m * 4 + 0];
    float qa1 = qa[(size_t)m * 4 + 1];
    float qa2 = qa[(size_t)m * 4 + 2];
    float qa3 = qa[(size_t)m * 4 + 3];
    const float* kbb = kb + (size_t)(b << 10) * 4;

    uchar4 c4 = *(const uchar4*)(code + (size_t)m * NN + 4 * t);
    float l0, l1, l2, l3;
    {
        unsigned char cc[4] = {c4.x, c4.y, c4.z, c4.w};
        float lv[4];
#pragma unroll
        for (int jj = 0; jj < 4; ++jj) {
            int j = 4 * t + jj;
            float4 k4 = *(const float4*)(kbb + (size_t)j * 4);
            unsigned char c = cc[jj];
            float kv = (c == 0) ? k4.x : ((c == 1) ? k4.y : ((c == 2) ? k4.z : k4.w));
            float qv = (c == 0) ? qa0 : ((c == 1) ? qa1 : ((c == 2) ? qa2 : qa3));
            float s = qv + kv;
            s = s > 0.f ? s : 0.2f * s;
            lv[jj] = (c == 255) ? -9.0e15f : ((c == 254) ? 0.f : s);
        }
        l0 = lv[0]; l1 = lv[1]; l2 = lv[2]; l3 = lv[3];
    }

    float lmax = fmaxf(fmaxf(l0, l1), fmaxf(l2, l3));
    for (int o = 32; o > 0; o >>= 1) lmax = fmaxf(lmax, __shfl_down(lmax, o));
    if ((t & 63) == 0) red[t >> 6] = lmax;
    __syncthreads();
    lmax = fmaxf(fmaxf(red[0], red[1]), fmaxf(red[2], red[3]));

    float e0 = __expf(l0 - lmax), e1 = __expf(l1 - lmax);
    float e2 = __expf(l2 - lmax), e3 = __expf(l3 - lmax);
    float lsum = (e0 + e1) + (e2 + e3);
    for (int o = 32; o > 0; o >>= 1) lsum += __shfl_down(lsum, o);
    if ((t & 63) == 0) red2[t >> 6] = lsum;
    __syncthreads();
    lsum = red2[0] + red2[1] + red2[2] + red2[3];
    float inv = 1.0f / lsum;

    ushort4 o4;
    o4.x = f2bu(e0 * inv); o4.y = f2bu(e1 * inv);
    o4.z = f2bu(e2 * inv); o4.w = f2bu(e3 * inv);
    ((ushort4*)(prob + (size_t)m * NN))[t] = o4;
}

// ---------------------------------------------------------------------------
extern "C" void kernel_launch(void* const* d_in, const int* in_sizes, int n_in,
                              void* d_out, int out_size, void* d_ws, size_t ws_size,
                              hipStream_t stream) {
    const float* ents = (const float*)d_in[0];
    const float* mask = (const float*)d_in[1];
    const float* qenc = (const float*)d_in[2];
    const int* adj = (const int*)d_in[3];
    const int* types = (const int*)d_in[4];
    const float* initm = (const float*)d_in[5];
    const float* w_qin = (const float*)d_in[6];
    const float* b_qin = (const float*)d_in[7];
    const float* w_qt = (const float*)d_in[8];
    const float* b_qt = (const float*)d_in[9];
    const float* w_pl = (const float*)d_in[10];
    const float* b_pl = (const float*)d_in[11];
    const float* w_pc = (const float*)d_in[12];
    const float* b_pc = (const float*)d_in[13];
    const float* w_q = (const float*)d_in[14];
    const float* b_q = (const float*)d_in[15];
    const float* w_k = (const float*)d_in[16];
    const float* b_k = (const float*)d_in[17];
    const float* w_v = (const float*)d_in[18];
    const float* b_v = (const float*)d_in[19];
    const float* w_pk = (const float*)d_in[20];
    const float* b_pk = (const float*)d_in[21];
    const float* w_pv = (const float*)d_in[22];
    const float* b_pv = (const float*)d_in[23];
    const float* wes = (const float*)d_in[24];
    const float* w_mu = (const float*)d_in[25];
    const float* b_mu = (const float*)d_in[26];
    const float* w_cb = (const float*)d_in[27];
    const float* b_cb = (const float*)d_in[28];
    (void)in_sizes; (void)n_in; (void)out_size; (void)ws_size;

    char* p = (char*)d_ws;
    auto carve = [&](size_t bytes) {
        char* r = p;
        p += (bytes + 255) & ~(size_t)255;
        return r;
    };
    // fp32 smalls
    float* q_base = (float*)carve((size_t)NB * DD * 4);
    float* cmd = (float*)carve((size_t)NT_ITER * NB * DD * 4);
    float* pk = (float*)carve((size_t)NT_ITER * NB * DD * 4);
    float* pv = (float*)carve((size_t)NT_ITER * NB * DD * 4);
    float* qa = (float*)carve((size_t)MM * 4 * 4);
    float* kb = (float*)carve((size_t)MM * 4 * 4);
    float* wqtw = (float*)carve((size_t)64 * 3072 * 4);  // rows 0..3 used
    float* wkeff = (float*)carve((size_t)64 * 3072 * 4); // row t*16+b*4+e
    float* cq = (float*)carve(4 * 4);
    float* ck = (float*)carve(64 * 4);
    float* bcomb = (float*)carve((size_t)3072 * 4);
    float* vent = (float*)carve((size_t)MM * DD * 4); // ents @ Wv[:, :D]^T (fp32)
    float* vxc = (float*)carve((size_t)MM * DD * 4);  // vent + b_v + xc @ WvB1 (fp32)
    float* muxc = (float*)carve((size_t)MM * DD * 4); // b_mu + xc @ WmuB1 (fp32)
    // bf16 copies
    bf16* initm_bf = (bf16*)carve((size_t)DD * 2);
    bf16* ents_bf = (bf16*)carve((size_t)MM * DD * 2);
    bf16* wpl_bf = (bf16*)carve((size_t)DD * DD * 2);
    bf16* wpc_bf = (bf16*)carve((size_t)DD * DD * 2);
    bf16* wv_bf = (bf16*)carve((size_t)DD * 3 * DD * 2);
    bf16* wmu_bf = (bf16*)carve((size_t)DD * 2 * DD * 2);
    bf16* wcb_bf = (bf16*)carve((size_t)DD * 2 * DD * 2);
    bf16* wqT_bf = (bf16*)carve((size_t)3 * DD * DD * 2); // w_q^T (3072 x 1024)
    bf16* wkT_bf = (bf16*)carve((size_t)3 * DD * DD * 2); // w_k^T
    bf16* wcomb = (bf16*)carve((size_t)3 * DD * DD * 2);  // [Wpc; WvB1; WmuB1]
    bf16* Aq = (bf16*)carve((size_t)64 * DD * 2);
    bf16* Ak = (bf16*)carve((size_t)64 * DD * 2);
    // uint8 adj code table (loop-invariant)
    unsigned char* code = (unsigned char*)carve((size_t)MM * NN);
    // bf16 activations
    bf16* x_ctx = (bf16*)carve((size_t)MM * DD * 2);
    bf16* xc = (bf16*)carve((size_t)MM * DD * 2);
    bf16* pl = (bf16*)carve((size_t)MM * DD * 2);
    bf16* plpc = (bf16*)carve((size_t)MM * DD * 2); // dead after k_qakb2 -> reused as vT
    bf16* vbuf = (bf16*)carve((size_t)MM * DD * 2);
    bf16* msg = (bf16*)carve((size_t)MM * DD * 2);
    bf16* prob = (bf16*)carve((size_t)NB * NN * NN * 2);
    bf16* vT = plpc;

    const dim3 blk(256);
    const dim3 g128(32, 16, 1);  // M=4096, N=1024, 128x64 tiles -> 512 blocks
    const dim3 gBig(32, 48, 1);  // M=4096, N=3072 fused xc-GEMM -> 1536 blocks
    const dim3 gMsg(8, 16, NB);  // per-batch M=1024 -> 512 blocks
    const dim3 gPre(1, 48, 1);   // M=64, N=3072 precompute GEMMs (64x64 config)

    // All fp32->bf16 conversions in one launch, then transposes + code table.
    k_f2b_all<<<13313, blk, 0, stream>>>(initm, ents, w_pl, w_pc, w_v, w_mu, w_cb,
                                         initm_bf, ents_bf, wpl_bf, wpc_bf, wv_bf, wmu_bf, wcb_bf);
    k_transw2<<<dim3(96, 32, 2), dim3(32, 8), 0, stream>>>(w_q, w_k, wqT_bf, wkT_bf);
    k_adjcode<<<4096, blk, 0, stream>>>(adj, types, code, MM * NN / 4);
    k_buildcomb<<<3072, blk, 0, stream>>>(wpc_bf, wv_bf, wmu_bf, b_pc, b_v, b_mu, wcomb, bcomb);

    k_qbase<<<1024, blk, 0, stream>>>(qenc, w_qin, b_qin, q_base);
    k_cmd<<<4096, blk, 0, stream>>>(q_base, w_qt, b_qt, cmd);
    k_pkpv<<<8192, blk, 0, stream>>>(cmd, w_pk, b_pk, w_pv, b_pv, pk, pv);
    k_init<<<2048, blk, 0, stream>>>(initm_bf, mask, x_ctx, xc);

    // q/k collapse precompute: A matrices, consts, then two tiny MFMA GEMMs.
    k_build_sc<<<512, blk, 0, stream>>>(pk, wes, Aq, Ak);
    k_consts<<<68, 64, 0, stream>>>(b_q, b_k, pk, wes, cq, ck);
    // wqtw(64x3072,f32) = Aq @ wqT^T ; wkeff = Ak @ wkT^T
    k_gemm_t<32, 32><<<gPre, blk, 0, stream>>>(Aq, nullptr, nullptr, wqT_bf, nullptr, wqtw,
                                               nullptr, nullptr, nullptr, nullptr, nullptr,
                                               0, 1, 1, 1024, 3072, 0, 0, 0);
    k_gemm_t<32, 32><<<gPre, blk, 0, stream>>>(Ak, nullptr, nullptr, wkT_bf, nullptr, wkeff,
                                               nullptr, nullptr, nullptr, nullptr, nullptr,
                                               0, 1, 1, 1024, 3072, 0, 0, 0);

    // Loop-invariant GEMMs:
    // pl = ents @ w_pl.T + b_pl
    k_gemm_t<64, 32><<<g128, blk, 0, stream>>>(ents_bf, nullptr, nullptr, wpl_bf, b_pl, pl,
                                               nullptr, nullptr, nullptr, nullptr, nullptr,
                                               0, 0, 1, 1024, 1024, 0, 0, 0);
    // vent = ents @ w_v[:, :D].T  (fp32, no bias/mul)
    k_gemm_t<64, 32><<<g128, blk, 0, stream>>>(ents_bf, nullptr, nullptr, wv_bf, nullptr, vent,
                                               nullptr, nullptr, nullptr, nullptr, nullptr,
                                               0, 1, 1, 3072, 1024, 0, 0, 0);

    for (int t = 0; t < NT_ITER; ++t) {
        // Fused xc-GEMM (N=3072): plpc=(xc@Wpc+b_pc)*pl ; vxc=xc@WvB1+b_v+vent ;
        // muxc=xc@WmuB1+b_mu
        k_gemm_t<64, 32><<<gBig, blk, 0, stream>>>(xc, nullptr, nullptr, wcomb, bcomb, plpc,
                                                   pl, vent, nullptr, vxc, muxc,
                                                   4, 0, 1, 1024, 1024, 0, 0, 0);
        // v = (vxc + plpc @ WvB2) * pv[t,b,:]
        k_gemm_t<64, 32><<<g128, blk, 0, stream>>>(plpc, nullptr, nullptr, wv_bf + 2048, nullptr, vbuf,
                                                   pv + (size_t)t * NB * DD, vxc, nullptr, nullptr, nullptr,
                                                   2, 0, 1, 3072, 1024, 0, 0, 0);
        // qa/kb via collapsed projections
        k_qakb2<<<4096, blk, 0, stream>>>(ents_bf, xc, plpc,
                                          wqtw, wkeff + (size_t)t * 16 * 3072,
                                          cq, ck + t * 16, qa, kb);
        k_transpose<<<dim3(32, 32, NB), dim3(32, 8), 0, stream>>>(vbuf, vT);
        k_attn<<<4096, blk, 0, stream>>>(code, qa, kb, prob);
        // message[b] = prob[b] @ v[b]  (NT with W = vT[b])
        k_gemm_t<64, 32><<<gMsg, blk, 0, stream>>>(prob, nullptr, nullptr, vT, nullptr, msg,
                                                   nullptr, nullptr, nullptr, nullptr, nullptr,
                                                   0, 0, 1, 1024, 1024,
                                                   (long long)NN * NN, (long long)DD * NN, (long long)NN * DD);
        // x_ctx = muxc + msg @ WmuB2 ; xc = x_ctx * mask (dual store, mode 3)
        k_gemm_t<64, 32><<<g128, blk, 0, stream>>>(msg, nullptr, nullptr, wmu_bf + 1024, nullptr, x_ctx,
                                                   mask, muxc, xc, nullptr, nullptr,
                                                   3, 0, 1, 2048, 1024, 0, 0, 0);
    }
    // out = [ents, x_ctx] @ w_cb.T + b_cb  (fp32 store)
    k_gemm_t<64, 32><<<g128, blk, 0, stream>>>(ents_bf, x_ctx, nullptr, wcb_bf, b_cb, (float*)d_out,
                                               nullptr, nullptr, nullptr, nullptr, nullptr,
                                               0, 1, 2, 2048, 1024, 0, 0, 0);
}

// Round 11
// 927.774 us; speedup vs baseline: 1.1576x; 1.1576x over previous
//
#include <hip/hip_runtime.h>
#include <hip/hip_bf16.h>
#include <stdint.h>
#include <stddef.h>

// QDGAT forward, MI355X gfx950.
// Round 18: BISECT after two consecutive "container failed twice" on the
// R16/R17 source (R14's source passed cleanly). The only never-verified
// component in R16 was k_attn_tr (attn+transpose fusion) -- dropped. This
// build = R14's dataflow (best measured, 940.5us) + R15's verified preamble
// merges (k_f2b_all, k_transw2; both ran in R15's passing bench) + separate
// k_attn (code-table) and k_transpose (both verified in R14). Every kernel
// here has passed on hardware at least once. If this fails too, it's infra.
// GEMM core: R10 config (128x64 tile, wave 64x32, 3-buffer counted-vmcnt,
// both-sides XOR bank swizzle) -- measured optimum of 6 structures.
// Inputs/outputs fp32; GEMM operands bf16 (absmax 0.031, budget 0.11).

typedef __hip_bfloat16 bf16;
typedef __attribute__((ext_vector_type(8))) short short8;
typedef __attribute__((ext_vector_type(4))) float floatx4;

#define NB 4
#define NN 1024
#define DD 1024
#define NT_ITER 4
#define MM (NB * NN) // 4096

static __device__ __forceinline__ float b2f(bf16 x) { return __bfloat162float(x); }
static __device__ __forceinline__ bf16 f2b(float x) { return __float2bfloat16(x); }
static __device__ __forceinline__ unsigned short f2bu(float x) {
    bf16 h = __float2bfloat16(x);
    unsigned short u;
    __builtin_memcpy(&u, &h, 2);
    return u;
}
static __device__ __forceinline__ float bu2f(unsigned short u) {
    unsigned int t = (unsigned int)u << 16;
    float f;
    __builtin_memcpy(&f, &t, 4);
    return f;
}

// global -> LDS direct DMA, 16 B per lane. LDS dest = wave-uniform base + lane*16.
static __device__ __forceinline__ void gl_lds16(const void* g, void* l) {
    __builtin_amdgcn_global_load_lds(
        (const __attribute__((address_space(1))) unsigned int*)g,
        (__attribute__((address_space(3))) unsigned int*)l, 16, 0, 0);
}

template <int N>
static __device__ __forceinline__ void s_wait_vmcnt() {
    if constexpr (N == 0)      asm volatile("s_waitcnt vmcnt(0)" ::: "memory");
    else if constexpr (N == 4) asm volatile("s_waitcnt vmcnt(4)" ::: "memory");
    else if constexpr (N == 6) asm volatile("s_waitcnt vmcnt(6)" ::: "memory");
    else if constexpr (N == 8) asm volatile("s_waitcnt vmcnt(8)" ::: "memory");
}

// ---------------------------------------------------------------------------
// All fp32 -> bf16 conversions in one launch (segment table by block range).
// float4-group cumulative offsets:
//   initm 256 | ents 1048576 | wpl 262144 | wpc 262144 | wv 786432
//   | wmu 524288 | wcb 524288  => total 3408128 groups (13313 blocks exact)
// ---------------------------------------------------------------------------
__global__ void k_f2b_all(const float* __restrict__ initm, const float* __restrict__ ents,
                          const float* __restrict__ wpl, const float* __restrict__ wpc,
                          const float* __restrict__ wv, const float* __restrict__ wmu,
                          const float* __restrict__ wcb,
                          bf16* __restrict__ initm_bf, bf16* __restrict__ ents_bf,
                          bf16* __restrict__ wpl_bf, bf16* __restrict__ wpc_bf,
                          bf16* __restrict__ wv_bf, bf16* __restrict__ wmu_bf,
                          bf16* __restrict__ wcb_bf) {
    long i = (long)blockIdx.x * 256 + threadIdx.x;
    const float* src;
    bf16* dst;
    long off;
    if (i < 1048832) {
        if (i < 256) { src = initm; dst = initm_bf; off = i; }
        else { src = ents; dst = ents_bf; off = i - 256; }
    } else if (i < 1573120) {
        if (i < 1310976) { src = wpl; dst = wpl_bf; off = i - 1048832; }
        else { src = wpc; dst = wpc_bf; off = i - 1310976; }
    } else if (i < 2359552) { src = wv; dst = wv_bf; off = i - 1573120; }
    else if (i < 2883840) { src = wmu; dst = wmu_bf; off = i - 2359552; }
    else { src = wcb; dst = wcb_bf; off = i - 2883840; }
    float4 v = ((const float4*)src)[off];
    ushort4 o;
    o.x = f2bu(v.x); o.y = f2bu(v.y); o.z = f2bu(v.z); o.w = f2bu(v.w);
    ((ushort4*)dst)[off] = o;
}

// ---------------------------------------------------------------------------
// fp32 (1024 x 3072) -> bf16 transposed (3072 x 1024); z selects w_q / w_k.
// ---------------------------------------------------------------------------
__global__ void k_transw2(const float* __restrict__ srcq, const float* __restrict__ srck,
                          bf16* __restrict__ dstq, bf16* __restrict__ dstk) {
    __shared__ float tile[32][33];
    const float* src = blockIdx.z ? srck : srcq;
    bf16* dst = blockIdx.z ? dstk : dstq;
    int c0 = blockIdx.x * 32;
    int r0 = blockIdx.y * 32;
    int tx = threadIdx.x, ty = threadIdx.y; // (32,8)
    for (int i = 0; i < 32; i += 8)
        tile[ty + i][tx] = src[(size_t)(r0 + ty + i) * 3072 + c0 + tx];
    __syncthreads();
    for (int i = 0; i < 32; i += 8)
        dst[(size_t)(c0 + ty + i) * 1024 + r0 + tx] = f2b(tile[tx][ty + i]);
}

// ---------------------------------------------------------------------------
// adj (int32, loop-invariant) -> uint8 code table, 4 elements/thread.
// code: 255 = masked (adj==0), 254 = zero-logit (type bit off), else adj-1.
// ---------------------------------------------------------------------------
__global__ void k_adjcode(const int* __restrict__ adj, const int* __restrict__ typesPtr,
                          unsigned char* __restrict__ code, int n4) {
    int i = blockIdx.x * 256 + threadIdx.x;
    if (i >= n4) return;
    int types = typesPtr[0];
    int4 a4 = ((const int4*)adj)[i];
    uchar4 c;
    int a;
    a = a4.x; c.x = (a == 0) ? 255 : (((types >> a) & 1) ? (unsigned char)(a - 1) : 254);
    a = a4.y; c.y = (a == 0) ? 255 : (((types >> a) & 1) ? (unsigned char)(a - 1) : 254);
    a = a4.z; c.z = (a == 0) ? 255 : (((types >> a) & 1) ? (unsigned char)(a - 1) : 254);
    a = a4.w; c.w = (a == 0) ? 255 : (((types >> a) & 1) ? (unsigned char)(a - 1) : 254);
    ((uchar4*)code)[i] = c;
}

// ---------------------------------------------------------------------------
// Build A matrices for the wqtw / wkeff GEMMs (64 x 1024 bf16 each).
// ---------------------------------------------------------------------------
__global__ void k_build_sc(const float* __restrict__ pk, const float* __restrict__ wes,
                           bf16* __restrict__ Aq, bf16* __restrict__ Ak) {
    int i = blockIdx.x * 256 + threadIdx.x; // 0..131071
    int half = i >> 16;
    int j = i & 65535;
    int row = j >> 10, d = j & 1023;
    if (half == 0) {
        Aq[j] = (row < 4) ? f2b(wes[(size_t)row * 2048 + d]) : f2b(0.f);
    } else {
        int t = row >> 4, b = (row >> 2) & 3, e = row & 3;
        Ak[j] = f2b(pk[((size_t)t * NB + b) * DD + d] * wes[(size_t)e * 2048 + 1024 + d]);
    }
}

// ---------------------------------------------------------------------------
// Wave-per-output GEMVs (coalesced weight-row reads, shuffle reduce).
// ---------------------------------------------------------------------------
__global__ __launch_bounds__(256) void k_qbase(const float* __restrict__ qenc, const float* __restrict__ w,
                                               const float* __restrict__ b, float* __restrict__ out) {
    int o = blockIdx.x * 4 + (threadIdx.x >> 6);
    int lane = threadIdx.x & 63;
    int n = o >> 2, r = o & 3;
    const float* xr = qenc + (size_t)r * DD;
    const float* wr = w + (size_t)n * DD;
    float s = 0.f;
    for (int d = lane; d < DD; d += 64) s += xr[d] * wr[d];
    for (int off = 32; off; off >>= 1) s += __shfl_down(s, off);
    if (lane == 0) {
        s += b[n];
        out[(size_t)r * DD + n] = s > 0.f ? s : (expf(s) - 1.0f); // ELU
    }
}

__global__ __launch_bounds__(256) void k_cmd(const float* __restrict__ qb, const float* __restrict__ w_qt,
                                             const float* __restrict__ b_qt, float* __restrict__ cmd) {
    int o = blockIdx.x * 4 + (threadIdx.x >> 6);
    int lane = threadIdx.x & 63;
    int r = o & 3, n = (o >> 2) & 1023, t = o >> 12;
    const float* xr = qb + (size_t)r * DD;
    const float* wr = w_qt + ((size_t)t * DD + n) * DD;
    float s = 0.f;
    for (int d = lane; d < DD; d += 64) s += xr[d] * wr[d];
    for (int off = 32; off; off >>= 1) s += __shfl_down(s, off);
    if (lane == 0) cmd[((size_t)t * NB + r) * DD + n] = s + b_qt[t * DD + n];
}

__global__ __launch_bounds__(256) void k_pkpv(const float* __restrict__ cmd,
                                              const float* __restrict__ w_pk, const float* __restrict__ b_pk,
                                              const float* __restrict__ w_pv, const float* __restrict__ b_pv,
                                              float* __restrict__ pk, float* __restrict__ pv) {
    int o = blockIdx.x * 4 + (threadIdx.x >> 6);
    int lane = threadIdx.x & 63;
    int n = o >> 5, half = (o >> 4) & 1, pair = o & 15;
    const float* xr = cmd + (size_t)pair * DD;
    const float* wr = (half ? w_pv : w_pk) + (size_t)n * DD;
    float s = 0.f;
    for (int d = lane; d < DD; d += 64) s += xr[d] * wr[d];
    for (int off = 32; off; off >>= 1) s += __shfl_down(s, off);
    if (lane == 0)
        (half ? pv : pk)[(size_t)pair * DD + n] = s + (half ? b_pv : b_pk)[n];
}

// One wave per output (68 outputs): cq[0..3], ck[0..63].
__global__ void k_consts(const float* __restrict__ b_q, const float* __restrict__ b_k,
                         const float* __restrict__ pk, const float* __restrict__ wes,
                         float* __restrict__ cq, float* __restrict__ ck) {
    int o = blockIdx.x;
    int lane = threadIdx.x;
    float s = 0.f;
    if (o < 4) {
        for (int d = lane; d < 1024; d += 64) s += b_q[d] * wes[(size_t)o * 2048 + d];
    } else {
        int oo = o - 4;
        int t = oo >> 4, b = (oo >> 2) & 3, e = oo & 3;
        for (int d = lane; d < 1024; d += 64)
            s += b_k[d] * pk[((size_t)t * NB + b) * DD + d] * wes[(size_t)e * 2048 + 1024 + d];
    }
    for (int off = 32; off; off >>= 1) s += __shfl_down(s, off);
    if (lane == 0) {
        if (o < 4) cq[o] = s;
        else ck[o - 4] = s;
    }
}

// ---------------------------------------------------------------------------
// qa[m,e], kb[m,e] via collapsed projections: block per row m.
// Vectorized: thread t owns d = 4t..4t+3 (ushort4 row load + float4 weights).
// ---------------------------------------------------------------------------
__global__ __launch_bounds__(256) void k_qakb2(const bf16* __restrict__ ents, const bf16* __restrict__ xc,
                                               const bf16* __restrict__ plpc,
                                               const float* __restrict__ wqtw, const float* __restrict__ wkeff_t,
                                               const float* __restrict__ cq, const float* __restrict__ ck_t,
                                               float* __restrict__ qa, float* __restrict__ kb) {
    __shared__ float red[4][8];
    int m = blockIdx.x;
    int b = m >> 10;
    int t = threadIdx.x;
    float aq[4] = {0.f, 0.f, 0.f, 0.f}, ak[4] = {0.f, 0.f, 0.f, 0.f};
    const bf16* rows[3] = {ents + (size_t)m * DD, xc + (size_t)m * DD, plpc + (size_t)m * DD};
#pragma unroll
    for (int c = 0; c < 3; ++c) {
        ushort4 rv = *(const ushort4*)(rows[c] + 4 * t);
        float xv0 = bu2f(rv.x), xv1 = bu2f(rv.y), xv2 = bu2f(rv.z), xv3 = bu2f(rv.w);
        const float* wq = wqtw + c * 1024 + 4 * t;
        const float* wk = wkeff_t + (size_t)b * 4 * 3072 + c * 1024 + 4 * t;
#pragma unroll
        for (int e = 0; e < 4; ++e) {
            float4 q4 = *(const float4*)(wq + (size_t)e * 3072);
            float4 k4 = *(const float4*)(wk + (size_t)e * 3072);
            aq[e] += xv0 * q4.x + xv1 * q4.y + xv2 * q4.z + xv3 * q4.w;
            ak[e] += xv0 * k4.x + xv1 * k4.y + xv2 * k4.z + xv3 * k4.w;
        }
    }
#pragma unroll
    for (int e = 0; e < 4; ++e) {
        float v = aq[e];
        for (int o = 32; o; o >>= 1) v += __shfl_down(v, o);
        if ((t & 63) == 0) red[t >> 6][e] = v;
        v = ak[e];
        for (int o = 32; o; o >>= 1) v += __shfl_down(v, o);
        if ((t & 63) == 0) red[t >> 6][e + 4] = v;
    }
    __syncthreads();
    if (t < 8) {
        float s = red[0][t] + red[1][t] + red[2][t] + red[3][t];
        if (t < 4) qa[(size_t)m * 4 + t] = s + cq[t];
        else kb[(size_t)m * 4 + (t - 4)] = s + ck_t[b * 4 + (t - 4)];
    }
}

// ---------------------------------------------------------------------------
// Init: x_ctx = broadcast(initm); xc = initm * mask (per row).
// ---------------------------------------------------------------------------
__global__ void k_init(const bf16* __restrict__ initm_bf, const float* __restrict__ mask,
                       bf16* __restrict__ x_ctx, bf16* __restrict__ xc) {
    int i = blockIdx.x * 256 + threadIdx.x; // uint4 groups, MM*DD/8
    uint4 v = ((const uint4*)initm_bf)[i & 127];
    ((uint4*)x_ctx)[i] = v;
    float mk = mask[i >> 7];
    unsigned short* u = (unsigned short*)&v;
#pragma unroll
    for (int j = 0; j < 8; ++j) u[j] = f2bu(bu2f(u[j]) * mk);
    ((uint4*)xc)[i] = v;
}

// ---------------------------------------------------------------------------
// BMxBN-tile GEMM: C[m,n] = sum_c A_c[m,k]*W[n,c*1024+k] (+bias)(+addC)(epilogue)
// Template WM, WN = wave-tile. Big GEMMs: <64,32> (BM=128, BN=64, R10 config,
// best measured). Precompute: <32,32>. BK=64. 4 waves as 2x2.
// Counted-vmcnt deep pipeline: 3 LDS buffers, tiles staged 2 ahead, wait
// vmcnt(SPW) per K-step (not 0), single raw s_barrier per K-step.
// Hazard proof: stage at iter kt targets buf[(kt+2)%3] = buf[(kt-1)%3]; every
// wave executed s_waitcnt lgkmcnt(0) at the end of iter kt-1 before arriving
// at iter kt's barrier, so after the barrier no wave can still be reading it.
// Tile kt's loads are proven landed by vmcnt(SPW).
// XOR bank swizzle both-sides (rule 21): linear LDS dest, pre-swizzled GLOBAL
// source column (scol ^= srow<<3, 16B granules), same XOR on ds_read side.
// A_c lda=1024; W row-major ldw; C row-major ldc. addC fp32, same index as C.
// mulmode: 0 none, 1 bf16 mul[m*1024+n], 2 f32 mul[(m>>10)*1024+n],
//          3 dual-store: C=val (bf16), C2=val*((f32*)mul)[gm] (bf16).
// ---------------------------------------------------------------------------
template <int WM, int WN>
__device__ __forceinline__ void gemm_core(
    const bf16* __restrict__ A0, const bf16* __restrict__ A1, const bf16* __restrict__ A2,
    const bf16* __restrict__ W, const float* __restrict__ bias, void* __restrict__ C,
    const void* __restrict__ mul, const float* __restrict__ addC, bf16* __restrict__ C2,
    int mulmode, int storef32, int nchunks, int ldw, int ldc,
    int bm, int bn) {
    constexpr int BM = WM * 2;
    constexpr int BN = WN * 2;
    constexpr int MI = WM / 16;
    constexpr int NI = WN / 16;
    constexpr int SEGS = (BM + BN) / 8;
    constexpr int SPW = SEGS / 4;
    __shared__ bf16 sAB[3][(BM + BN) * 64];

    const int t = threadIdx.x;
    const int lane = t & 63;
    const int w = t >> 6;
    const int wm = (w & 1) * WM, wn = (w >> 1) * WN;
    const int srow = lane >> 3;
    const int scol = ((lane & 7) * 8) ^ (srow << 3);

    floatx4 acc[MI][NI];
#pragma unroll
    for (int i = 0; i < MI; ++i)
#pragma unroll
        for (int j = 0; j < NI; ++j) acc[i][j] = (floatx4){0.f, 0.f, 0.f, 0.f};

    const int lrow = lane & 15;
    const int kq = (lane >> 4) * 8;
    const int kx = (lane & 7) << 3;
    const int ktiles = nchunks * 16;

    auto stage = [&](int buf, int kt) {
        const int cidx = kt >> 4;
        const bf16* Ac = (cidx == 0) ? A0 : (cidx == 1 ? A1 : A2);
        const int klocal = (kt & 15) * 64;
        const int kglob = kt * 64;
#pragma unroll
        for (int s = 0; s < SPW; ++s) {
            int c = w * SPW + s;
            if (c < BM / 8) {
                const bf16* src = Ac + ((size_t)(bm * BM + c * 8 + srow)) * 1024 + klocal + scol;
                gl_lds16(src, &sAB[buf][c * 512]);
            } else {
                const bf16* src = W + ((size_t)(bn * BN + (c - BM / 8) * 8 + srow)) * (size_t)ldw + kglob + scol;
                gl_lds16(src, &sAB[buf][c * 512]);
            }
        }
    };

    stage(0, 0);
    if (ktiles > 1) stage(1, 1);
    int cur = 0, sb = 2;
    for (int kt = 0; kt < ktiles; ++kt) {
        if (kt + 1 < ktiles) s_wait_vmcnt<SPW>();
        else s_wait_vmcnt<0>();
        __builtin_amdgcn_s_barrier();
        __builtin_amdgcn_sched_barrier(0);
        short8 af[2][MI], bfr[2][NI];
#pragma unroll
        for (int ks = 0; ks < 2; ++ks) {
            const int ko = (ks * 32 + kq) ^ kx;
#pragma unroll
            for (int mi = 0; mi < MI; ++mi)
                af[ks][mi] = *(const short8*)&sAB[cur][(wm + mi * 16 + lrow) * 64 + ko];
#pragma unroll
            for (int ni = 0; ni < NI; ++ni)
                bfr[ks][ni] = *(const short8*)&sAB[cur][BM * 64 + (wn + ni * 16 + lrow) * 64 + ko];
        }
        if (kt + 2 < ktiles) stage(sb, kt + 2);
        __builtin_amdgcn_s_setprio(1);
#pragma unroll
        for (int ks = 0; ks < 2; ++ks)
#pragma unroll
            for (int mi = 0; mi < MI; ++mi)
#pragma unroll
                for (int ni = 0; ni < NI; ++ni)
                    acc[mi][ni] = __builtin_amdgcn_mfma_f32_16x16x32_bf16(af[ks][mi], bfr[ks][ni], acc[mi][ni], 0, 0, 0);
        __builtin_amdgcn_s_setprio(0);
        asm volatile("s_waitcnt lgkmcnt(0)" ::: "memory");
        __builtin_amdgcn_sched_barrier(0);
        cur = (cur == 2) ? 0 : cur + 1;
        sb = (sb == 2) ? 0 : sb + 1;
    }

    const int qrow = (lane >> 4) * 4;
#pragma unroll
    for (int mi = 0; mi < MI; ++mi) {
#pragma unroll
        for (int ni = 0; ni < NI; ++ni) {
            int gn = bn * BN + wn + ni * 16 + lrow;
            float bv = bias ? bias[gn] : 0.f;
#pragma unroll
            for (int r = 0; r < 4; ++r) {
                int gm = bm * BM + wm + mi * 16 + qrow + r;
                size_t ci = (size_t)gm * (size_t)ldc + gn;
                float val = acc[mi][ni][r] + bv;
                if (addC) val += addC[ci];
                if (mulmode == 1)
                    val *= b2f(((const bf16*)mul)[(size_t)gm * 1024 + gn]);
                else if (mulmode == 2)
                    val *= ((const float*)mul)[(size_t)(gm >> 10) * 1024 + gn];
                if (storef32) {
                    ((float*)C)[ci] = val;
                } else {
                    ((bf16*)C)[ci] = f2b(val);
                    if (mulmode == 3)
                        C2[ci] = f2b(val * ((const float*)mul)[gm]);
                }
            }
        }
    }
}

template <int WM, int WN>
__global__ __launch_bounds__(256) void k_gemm_t(
    const bf16* __restrict__ A0, const bf16* __restrict__ A1, const bf16* __restrict__ A2,
    const bf16* __restrict__ W, const float* __restrict__ bias, void* __restrict__ C,
    const void* __restrict__ mul, const float* __restrict__ addC, bf16* __restrict__ C2,
    int mulmode, int storef32, int nchunks, int ldw, int ldc,
    long long sA, long long sW, long long sC) {
    int bz = blockIdx.z;
    const bf16* A0b = A0 + (size_t)bz * sA;
    const bf16* Wb = W + (size_t)bz * sW;
    void* Cb = storef32 ? (void*)((float*)C + (size_t)bz * sC)
                        : (void*)((bf16*)C + (size_t)bz * sC);
    gemm_core<WM, WN>(A0b, A1, A2, Wb, bias, Cb, mul, addC, C2, mulmode, storef32, nchunks, ldw, ldc,
                      blockIdx.x, blockIdx.y);
}

// ---------------------------------------------------------------------------
// v (B,N,D) -> vT (B,D,N)
// ---------------------------------------------------------------------------
__global__ void k_transpose(const bf16* __restrict__ v, bf16* __restrict__ vT) {
    __shared__ bf16 tile[32][33];
    int b = blockIdx.z;
    int n0 = blockIdx.x * 32, d0 = blockIdx.y * 32;
    int tx = threadIdx.x, ty = threadIdx.y; // (32,8)
    for (int i = 0; i < 32; i += 8)
        tile[ty + i][tx] = v[((size_t)b * NN + n0 + ty + i) * DD + d0 + tx];
    __syncthreads();
    for (int i = 0; i < 32; i += 8)
        vT[((size_t)b * DD + d0 + ty + i) * NN + n0 + tx] = tile[tx][ty + i];
}

// ---------------------------------------------------------------------------
// Edge scores + masked softmax from the uint8 code table: one block per row.
// Thread t owns j = 4t..4t+3; logits live in registers; two block reductions.
// ---------------------------------------------------------------------------
__global__ __launch_bounds__(256) void k_attn(const unsigned char* __restrict__ code,
                                              const float* __restrict__ qa,
                                              const float* __restrict__ kb,
                                              bf16* __restrict__ prob) {
    __shared__ float red[4];
    __shared__ float red2[4];
    int m = blockIdx.x;
    int b = m >> 10;
    int t = threadIdx.x;
    float qa0 = qa[(size_t)m * 4 + 0];
    float qa1 = qa[(size_t)m * 4 + 1];
    float qa2 = qa[(size_t)m * 4 + 2];
    float qa3 = qa[(size_t)m * 4 + 3];
    const float* kbb = kb + (size_t)(b << 10) * 4;

    uchar4 c4 = *(const uchar4*)(code + (size_t)m * NN + 4 * t);
    float l0, l1, l2, l3;
    {
        unsigned char cc[4] = {c4.x, c4.y, c4.z, c4.w};
        float lv[4];
#pragma unroll
        for (int jj = 0; jj < 4; ++jj) {
            int j = 4 * t + jj;
            float4 k4 = *(const float4*)(kbb + (size_t)j * 4);
            unsigned char c = cc[jj];
            float kv = (c == 0) ? k4.x : ((c == 1) ? k4.y : ((c == 2) ? k4.z : k4.w));
            float qv = (c == 0) ? qa0 : ((c == 1) ? qa1 : ((c == 2) ? qa2 : qa3));
            float s = qv + kv;
            s = s > 0.f ? s : 0.2f * s;
            lv[jj] = (c == 255) ? -9.0e15f : ((c == 254) ? 0.f : s);
        }
        l0 = lv[0]; l1 = lv[1]; l2 = lv[2]; l3 = lv[3];
    }

    float lmax = fmaxf(fmaxf(l0, l1), fmaxf(l2, l3));
    for (int o = 32; o > 0; o >>= 1) lmax = fmaxf(lmax, __shfl_down(lmax, o));
    if ((t & 63) == 0) red[t >> 6] = lmax;
    __syncthreads();
    lmax = fmaxf(fmaxf(red[0], red[1]), fmaxf(red[2], red[3]));

    float e0 = __expf(l0 - lmax), e1 = __expf(l1 - lmax);
    float e2 = __expf(l2 - lmax), e3 = __expf(l3 - lmax);
    float lsum = (e0 + e1) + (e2 + e3);
    for (int o = 32; o > 0; o >>= 1) lsum += __shfl_down(lsum, o);
    if ((t & 63) == 0) red2[t >> 6] = lsum;
    __syncthreads();
    lsum = red2[0] + red2[1] + red2[2] + red2[3];
    float inv = 1.0f / lsum;

    ushort4 o4;
    o4.x = f2bu(e0 * inv); o4.y = f2bu(e1 * inv);
    o4.z = f2bu(e2 * inv); o4.w = f2bu(e3 * inv);
    ((ushort4*)(prob + (size_t)m * NN))[t] = o4;
}

// ---------------------------------------------------------------------------
extern "C" void kernel_launch(void* const* d_in, const int* in_sizes, int n_in,
                              void* d_out, int out_size, void* d_ws, size_t ws_size,
                              hipStream_t stream) {
    const float* ents = (const float*)d_in[0];
    const float* mask = (const float*)d_in[1];
    const float* qenc = (const float*)d_in[2];
    const int* adj = (const int*)d_in[3];
    const int* types = (const int*)d_in[4];
    const float* initm = (const float*)d_in[5];
    const float* w_qin = (const float*)d_in[6];
    const float* b_qin = (const float*)d_in[7];
    const float* w_qt = (const float*)d_in[8];
    const float* b_qt = (const float*)d_in[9];
    const float* w_pl = (const float*)d_in[10];
    const float* b_pl = (const float*)d_in[11];
    const float* w_pc = (const float*)d_in[12];
    const float* b_pc = (const float*)d_in[13];
    const float* w_q = (const float*)d_in[14];
    const float* b_q = (const float*)d_in[15];
    const float* w_k = (const float*)d_in[16];
    const float* b_k = (const float*)d_in[17];
    const float* w_v = (const float*)d_in[18];
    const float* b_v = (const float*)d_in[19];
    const float* w_pk = (const float*)d_in[20];
    const float* b_pk = (const float*)d_in[21];
    const float* w_pv = (const float*)d_in[22];
    const float* b_pv = (const float*)d_in[23];
    const float* wes = (const float*)d_in[24];
    const float* w_mu = (const float*)d_in[25];
    const float* b_mu = (const float*)d_in[26];
    const float* w_cb = (const float*)d_in[27];
    const float* b_cb = (const float*)d_in[28];
    (void)in_sizes; (void)n_in; (void)out_size; (void)ws_size;

    char* p = (char*)d_ws;
    auto carve = [&](size_t bytes) {
        char* r = p;
        p += (bytes + 255) & ~(size_t)255;
        return r;
    };
    // fp32 smalls
    float* q_base = (float*)carve((size_t)NB * DD * 4);
    float* cmd = (float*)carve((size_t)NT_ITER * NB * DD * 4);
    float* pk = (float*)carve((size_t)NT_ITER * NB * DD * 4);
    float* pv = (float*)carve((size_t)NT_ITER * NB * DD * 4);
    float* qa = (float*)carve((size_t)MM * 4 * 4);
    float* kb = (float*)carve((size_t)MM * 4 * 4);
    float* wqtw = (float*)carve((size_t)64 * 3072 * 4);  // rows 0..3 used
    float* wkeff = (float*)carve((size_t)64 * 3072 * 4); // row t*16+b*4+e
    float* cq = (float*)carve(4 * 4);
    float* ck = (float*)carve(64 * 4);
    float* vent = (float*)carve((size_t)MM * DD * 4); // ents @ Wv[:, :D]^T (fp32)
    // bf16 copies
    bf16* initm_bf = (bf16*)carve((size_t)DD * 2);
    bf16* ents_bf = (bf16*)carve((size_t)MM * DD * 2);
    bf16* wpl_bf = (bf16*)carve((size_t)DD * DD * 2);
    bf16* wpc_bf = (bf16*)carve((size_t)DD * DD * 2);
    bf16* wv_bf = (bf16*)carve((size_t)DD * 3 * DD * 2);
    bf16* wmu_bf = (bf16*)carve((size_t)DD * 2 * DD * 2);
    bf16* wcb_bf = (bf16*)carve((size_t)DD * 2 * DD * 2);
    bf16* wqT_bf = (bf16*)carve((size_t)3 * DD * DD * 2); // w_q^T (3072 x 1024)
    bf16* wkT_bf = (bf16*)carve((size_t)3 * DD * DD * 2); // w_k^T
    bf16* Aq = (bf16*)carve((size_t)64 * DD * 2);
    bf16* Ak = (bf16*)carve((size_t)64 * DD * 2);
    // uint8 adj code table (loop-invariant)
    unsigned char* code = (unsigned char*)carve((size_t)MM * NN);
    // bf16 activations
    bf16* x_ctx = (bf16*)carve((size_t)MM * DD * 2);
    bf16* xc = (bf16*)carve((size_t)MM * DD * 2);
    bf16* pl = (bf16*)carve((size_t)MM * DD * 2);
    bf16* plpc = (bf16*)carve((size_t)MM * DD * 2); // dead after k_qakb2 -> reused as vT
    bf16* vbuf = (bf16*)carve((size_t)MM * DD * 2);
    bf16* msg = (bf16*)carve((size_t)MM * DD * 2);
    bf16* prob = (bf16*)carve((size_t)NB * NN * NN * 2);
    bf16* vT = plpc;

    const dim3 blk(256);
    const dim3 g128(32, 16, 1);  // M=4096, N=1024, 128x64 tiles -> 512 blocks
    const dim3 gMsg(8, 16, NB);  // per-batch M=1024 -> 512 blocks
    const dim3 gPre(1, 48, 1);   // M=64, N=3072 precompute GEMMs (64x64 config)

    // Preamble: conversions (1 launch), transposes (1), code table (1).
    k_f2b_all<<<13313, blk, 0, stream>>>(initm, ents, w_pl, w_pc, w_v, w_mu, w_cb,
                                         initm_bf, ents_bf, wpl_bf, wpc_bf, wv_bf, wmu_bf, wcb_bf);
    k_transw2<<<dim3(96, 32, 2), dim3(32, 8), 0, stream>>>(w_q, w_k, wqT_bf, wkT_bf);
    k_adjcode<<<4096, blk, 0, stream>>>(adj, types, code, MM * NN / 4);

    k_qbase<<<1024, blk, 0, stream>>>(qenc, w_qin, b_qin, q_base);
    k_cmd<<<4096, blk, 0, stream>>>(q_base, w_qt, b_qt, cmd);
    k_pkpv<<<8192, blk, 0, stream>>>(cmd, w_pk, b_pk, w_pv, b_pv, pk, pv);
    k_init<<<2048, blk, 0, stream>>>(initm_bf, mask, x_ctx, xc);

    // q/k collapse precompute: A matrices, consts, then two tiny MFMA GEMMs.
    k_build_sc<<<512, blk, 0, stream>>>(pk, wes, Aq, Ak);
    k_consts<<<68, 64, 0, stream>>>(b_q, b_k, pk, wes, cq, ck);
    // wqtw(64x3072,f32) = Aq @ wqT^T ; wkeff = Ak @ wkT^T
    k_gemm_t<32, 32><<<gPre, blk, 0, stream>>>(Aq, nullptr, nullptr, wqT_bf, nullptr, wqtw,
                                               nullptr, nullptr, nullptr, 0, 1, 1, 1024, 3072, 0, 0, 0);
    k_gemm_t<32, 32><<<gPre, blk, 0, stream>>>(Ak, nullptr, nullptr, wkT_bf, nullptr, wkeff,
                                               nullptr, nullptr, nullptr, 0, 1, 1, 1024, 3072, 0, 0, 0);

    // Loop-invariant GEMMs:
    // pl = ents @ w_pl.T + b_pl
    k_gemm_t<64, 32><<<g128, blk, 0, stream>>>(ents_bf, nullptr, nullptr, wpl_bf, b_pl, pl,
                                               nullptr, nullptr, nullptr, 0, 0, 1, 1024, 1024, 0, 0, 0);
    // vent = ents @ w_v[:, :D].T  (fp32, no bias/mul)
    k_gemm_t<64, 32><<<g128, blk, 0, stream>>>(ents_bf, nullptr, nullptr, wv_bf, nullptr, vent,
                                               nullptr, nullptr, nullptr, 0, 1, 1, 3072, 1024, 0, 0, 0);

    for (int t = 0; t < NT_ITER; ++t) {
        // plpc = (xc @ w_pc.T + b_pc) * pl
        k_gemm_t<64, 32><<<g128, blk, 0, stream>>>(xc, nullptr, nullptr, wpc_bf, b_pc, plpc,
                                                   pl, nullptr, nullptr, 1, 0, 1, 1024, 1024, 0, 0, 0);
        // v = (vent + [xc, plpc] @ w_v[:, D:].T + b_v) * pv[t,b,:]
        k_gemm_t<64, 32><<<g128, blk, 0, stream>>>(xc, plpc, nullptr, wv_bf + 1024, b_v, vbuf,
                                                   pv + (size_t)t * NB * DD, vent, nullptr, 2, 0, 2, 3072, 1024, 0, 0, 0);
        // qa/kb via collapsed projections
        k_qakb2<<<4096, blk, 0, stream>>>(ents_bf, xc, plpc,
                                          wqtw, wkeff + (size_t)t * 16 * 3072,
                                          cq, ck + t * 16, qa, kb);
        k_transpose<<<dim3(32, 32, NB), dim3(32, 8), 0, stream>>>(vbuf, vT);
        k_attn<<<4096, blk, 0, stream>>>(code, qa, kb, prob);
        // message[b] = prob[b] @ v[b]  (NT with W = vT[b])
        k_gemm_t<64, 32><<<gMsg, blk, 0, stream>>>(prob, nullptr, nullptr, vT, nullptr, msg,
                                                   nullptr, nullptr, nullptr, 0, 0, 1, 1024, 1024,
                                                   (long long)NN * NN, (long long)DD * NN, (long long)NN * DD);
        // x_ctx = [xc, msg] @ w_mu.T + b_mu ; xc = x_ctx * mask (fused, mulmode 3)
        k_gemm_t<64, 32><<<g128, blk, 0, stream>>>(xc, msg, nullptr, wmu_bf, b_mu, x_ctx,
                                                   mask, nullptr, xc, 3, 0, 2, 2048, 1024, 0, 0, 0);
    }
    // out = [ents, x_ctx] @ w_cb.T + b_cb  (fp32 store)
    k_gemm_t<64, 32><<<g128, blk, 0, stream>>>(ents_bf, x_ctx, nullptr, wcb_bf, b_cb, (float*)d_out,
                                               nullptr, nullptr, nullptr, 0, 1, 2, 2048, 1024, 0, 0, 0);
}